// Round 11
// baseline (440.477 us; speedup 1.0000x reference)
//
#include <hip/hip_runtime.h>

// MoE top-2/8: routed bf16-MFMA grouped GEMMs.
// R11: 32x32x16 MFMA (half the MFMA instructions, higher-ceiling shape).
// BK=64, R8's race-audited stage/guard schedule. gemm1 B-rows remapped so
// each lane holds the swiGLU a/b pair for the same hcol.

#define N_TOK 8192
#define DIM   1024
#define HID   2048
#define NEXP  8
#define NK    (N_TOK * 2)
#define MAXT2 72    // max 256-row tiles (64 full + 8 partial)
#define MAXT1 136   // max 128-row tiles (128 full + 8 partial)

typedef __attribute__((ext_vector_type(8))) short short8;
typedef __attribute__((ext_vector_type(16))) float f32x16;

#define BARX() __builtin_amdgcn_s_barrier()
#define FEN()  asm volatile("" ::: "memory")
#define VMW4() asm volatile("s_waitcnt vmcnt(4)" ::: "memory")
#define VMW2() asm volatile("s_waitcnt vmcnt(2)" ::: "memory")
#define VMW0() asm volatile("s_waitcnt vmcnt(0)" ::: "memory")
#define LGKM0() asm volatile("s_waitcnt lgkmcnt(0)" ::: "memory")
#define PRIO(p) __builtin_amdgcn_s_setprio(p)

static __device__ __forceinline__ unsigned short f2bf(float f) {
  unsigned int u = __float_as_uint(f);
  u += 0x7fffu + ((u >> 16) & 1u);
  return (unsigned short)(u >> 16);
}

static __device__ __forceinline__ void glds16(const void* g, void* l) {
  __builtin_amdgcn_global_load_lds(
      (const __attribute__((address_space(1))) unsigned int*)g,
      (__attribute__((address_space(3))) unsigned int*)l, 16, 0, 0);
}

// ================= prep: W1^T || W2^T || router || zero(out) ================
__device__ __forceinline__ void transpose_tile(const float* __restrict__ s,
                                               unsigned short* __restrict__ d,
                                               int R, int C, int c0, int r0,
                                               unsigned short (*tT)[68]) {
  int tid = threadIdx.x;
  int c = tid & 63, rq = tid >> 6;
#pragma unroll
  for (int q = 0; q < 4; ++q) {
    int rb = q * 16 + rq * 4;
    ushort4 v;
    v.x = f2bf(s[(size_t)(r0 + rb + 0) * C + c0 + c]);
    v.y = f2bf(s[(size_t)(r0 + rb + 1) * C + c0 + c]);
    v.z = f2bf(s[(size_t)(r0 + rb + 2) * C + c0 + c]);
    v.w = f2bf(s[(size_t)(r0 + rb + 3) * C + c0 + c]);
    *(ushort4*)&tT[c][rb] = v;
  }
  __syncthreads();
#pragma unroll
  for (int it = 0; it < 4; ++it) {
    int idx = it * 256 + tid;
    int cc = idx >> 4;
    int r4 = (idx & 15) * 4;
    *(ushort4*)(d + (size_t)(c0 + cc) * R + r0 + r4) = *(const ushort4*)&tT[cc][r4];
  }
}

__global__ __launch_bounds__(256) void prep_k(
    const float* __restrict__ x, const float* __restrict__ Wr,
    const float* __restrict__ W1, const float* __restrict__ W2,
    unsigned short* __restrict__ w1t, unsigned short* __restrict__ w2t,
    unsigned short* __restrict__ xb, int* __restrict__ te,
    float* __restrict__ tg, float* __restrict__ out) {
  __shared__ unsigned short tT[64][68];
  int bid = blockIdx.x;
  if (bid < 8192) {                       // W1 transpose
    int z = bid >> 10, rem = bid & 1023;
    int c0 = (rem & 63) * 64, r0 = (rem >> 6) * 64;
    transpose_tile(W1 + (size_t)z * DIM * 2 * HID,
                   w1t + (size_t)z * DIM * 2 * HID, DIM, 2 * HID, c0, r0, tT);
  } else if (bid < 12288) {               // W2 transpose
    int b2 = bid - 8192;
    int z = b2 >> 9, rem = b2 & 511;
    int c0 = (rem & 15) * 64, r0 = (rem >> 4) * 64;
    transpose_tile(W2 + (size_t)z * HID * DIM,
                   w2t + (size_t)z * HID * DIM, HID, DIM, c0, r0, tT);
  } else if (bid < 14336) {               // router (4 tokens, 1 wave each)
    int n = (bid - 12288) * 4 + (threadIdx.x >> 6);
    int lane = threadIdx.x & 63;
    float z[8];
#pragma unroll
    for (int e = 0; e < 8; ++e) z[e] = 0.f;
    const float* xr = x + (size_t)n * DIM;
    unsigned short* xbr = xb + (size_t)n * DIM;
#pragma unroll 4
    for (int i = 0; i < DIM / 64; ++i) {
      int d = lane + i * 64;
      float xv = xr[d];
      xbr[d] = f2bf(xv);
      float4 w0 = *(const float4*)(Wr + (size_t)d * 8);
      float4 w1 = *(const float4*)(Wr + (size_t)d * 8 + 4);
      z[0] += xv * w0.x; z[1] += xv * w0.y; z[2] += xv * w0.z; z[3] += xv * w0.w;
      z[4] += xv * w1.x; z[5] += xv * w1.y; z[6] += xv * w1.z; z[7] += xv * w1.w;
    }
    for (int off = 32; off; off >>= 1)
#pragma unroll
      for (int e = 0; e < 8; ++e) z[e] += __shfl_down(z[e], off);
    if (lane == 0) {
      int e0 = 0; float v0 = z[0];
#pragma unroll
      for (int e = 1; e < 8; ++e) if (z[e] > v0) { v0 = z[e]; e0 = e; }
      int e1 = -1; float v1 = -3.4e38f;
#pragma unroll
      for (int e = 0; e < 8; ++e) if (e != e0 && z[e] > v1) { v1 = z[e]; e1 = e; }
      float r = expf(v1 - v0);
      float s0 = 1.f / (1.f + r);
      te[n * 2] = e0; te[n * 2 + 1] = e1;
      tg[n * 2] = s0; tg[n * 2 + 1] = r * s0;
    }
  } else {                                // zero out
    int t = bid - 14336;
    float4* o4 = (float4*)out;
    int idx = t * 256 + threadIdx.x;
#pragma unroll
    for (int i = 0; i < 4; ++i) o4[idx + i * 524288] = (float4){0.f, 0.f, 0.f, 0.f};
  }
}

// ===== sortscan: one block; histogram -> offs/tl256/tl128, scatter ==========
__global__ __launch_bounds__(1024) void sortscan_k(
    const int* __restrict__ te, const float* __restrict__ tg,
    int* __restrict__ offs, int* __restrict__ tl256, int* __restrict__ tl128,
    int* __restrict__ rows, float* __restrict__ rowg) {
  __shared__ int hist[8];
  __shared__ int curs[8];
  int tid = threadIdx.x;
  if (tid < 8) hist[tid] = 0;
  __syncthreads();
  for (int i = tid; i < NK; i += 1024) atomicAdd(&hist[te[i]], 1);
  __syncthreads();
  if (tid == 0) {
    int o = 0, t2 = 0, t1 = 0;
    offs[0] = 0; tl256[0] = 0; tl128[0] = 0;
    for (int e = 0; e < NEXP; ++e) {
      curs[e] = o;
      o += hist[e];
      offs[e + 1] = o;
      t2 += (hist[e] + 255) >> 8;
      tl256[e + 1] = t2;
      t1 += (hist[e] + 127) >> 7;
      tl128[e + 1] = t1;
    }
  }
  __syncthreads();
  for (int i = tid; i < NK; i += 1024) {
    int e = te[i];
    int pos = atomicAdd(&curs[e], 1);
    rows[pos] = i >> 1;
    rowg[pos] = tg[i];
  }
}

// ======== 32x32x16-MFMA 8-phase BMx256 grouped GEMM, BK=64 ==================
// Per wave: BM/2 x 64 output = MW (BM/64) x 2 frags of 32x32.
// Phases per K-tile: P0 {aLo ks01, b ks01 | stage B(T+1).h0 | MFMA lo x ks01}
//   P1 {aLo ks23, b ks23 | B(T+1).h1 | MFMA lo x ks23}
//   P2 {aHi ks0-3 | A(T+2).h0 | MFMA hi x ks01 | lgkmcnt(0)}
//   P3 {A(T+2).h1 | MFMA hi x ks23 | vmcnt guard}
// A halves keyed on row bit (BM/2): hi-rows read only at P2 (drained by
// lgkmcnt(0) before P2's closing barrier) so the P3 h1-stage cannot race.
template <int GID, int BM>
__global__ __launch_bounds__(512, 2) void moe_gemm32(
    const unsigned short* __restrict__ Asrc,
    const unsigned short* __restrict__ Wt,
    const float* __restrict__ bias,
    unsigned short* __restrict__ hb,
    float* __restrict__ out,
    const int* __restrict__ rows,
    const float* __restrict__ rowg,
    const int* __restrict__ offs,
    const int* __restrict__ tl) {
  constexpr int KD = (GID == 0) ? DIM : HID;
  constexpr int NT = KD / 64;
  constexpr int MW = BM / 64;          // 32x32 m-frags per wave (4 or 2)
  constexpr int MH = MW / 2;           // frags per half
  constexpr int ASZ = BM * 64;         // A slab elements
  __shared__ unsigned short smem[2 * ASZ + 2 * 16384];

  int bt = blockIdx.x;
  if (bt >= tl[NEXP]) return;
  int e = 0;
  while (e < NEXP - 1 && bt >= tl[e + 1]) ++e;
  int rt = bt - tl[e];
  int base = offs[e];
  int cntE = offs[e + 1] - base;
  int row0 = rt * BM;
  int jb = blockIdx.y;

  int tid = threadIdx.x, lane = tid & 63, w = tid >> 6;
  int wr = w >> 2, wc = w & 3;

  // ---------- staging sources/dsts (pre-swizzled 16B k-granule) ----------
  int g8 = (((lane & 7) ^ ((lane >> 3) & 7)) * 8);
  // B: 2 halves x 2 slots, 2 glds/thread per half
  const unsigned short* bP[2][2];
  int bD[2][2];
#pragma unroll
  for (int hf = 0; hf < 2; ++hf)
#pragma unroll
    for (int s = 0; s < 2; ++s) {
      int q0 = w * 16 + s * 8;
      int rB = hf * 128 + q0 + (lane >> 3);
      if (GID == 0) {
        // B-row r -> (wave g = r>>6, half = (r>>5)&1, c = r&31):
        // hcol = jb*128 + g*32 + c ; w1row = hcol + half*HID
        int g = rB >> 6, rr = rB & 63;
        int hcol = jb * 128 + g * 32 + (rr & 31);
        int w1row = hcol + (rr >> 5) * HID;
        bP[hf][s] = Wt + ((size_t)e * 2 * HID + w1row) * DIM + g8;
      } else {
        int j0 = jb * 256;
        bP[hf][s] = Wt + ((size_t)e * DIM + (j0 + rB)) * HID + g8;
      }
      bD[hf][s] = (hf * 128 + q0) * 64;
    }
  // A: BM=256 -> 2 halves x 2 slots (bit6); BM=128 -> 2 halves x 1 (bit5)
  constexpr int AG = (BM == 256) ? 2 : 1;
  constexpr int HBIT = BM / 4;
  const unsigned short* aP[2][AG];
  int aD[2][AG];
#pragma unroll
  for (int hf = 0; hf < 2; ++hf)
#pragma unroll
    for (int s = 0; s < AG; ++s) {
      int rbA, rA;
      if (BM == 256) {
        int q0 = w * 16 + s * 8;
        rbA = (q0 < HBIT ? q0 : q0 + HBIT) + hf * HBIT;
        rA = rbA + (lane >> 3);
      } else {
        int q0 = w * 8;
        rbA = (q0 < HBIT ? q0 : q0 + HBIT) + hf * HBIT;
        rA = rbA + (lane >> 3);
      }
      int rr = row0 + rA; rr = rr < cntE ? rr : cntE - 1;
      if (GID == 0) {
        int tok = rows[base + rr];
        aP[hf][s] = Asrc + (size_t)tok * DIM + g8;
      } else {
        aP[hf][s] = Asrc + (size_t)(base + rr) * HID + g8;
      }
      aD[hf][s] = rbA * 64;
    }

  auto stA = [&](int t, int hf) {
    if (t < NT) {
#pragma unroll
      for (int s = 0; s < AG; ++s)
        glds16(aP[hf][s] + (size_t)t * 64, smem + (t & 1) * ASZ + aD[hf][s]);
    }
  };
  auto stB = [&](int t, int hf) {
    if (t < NT) {
#pragma unroll
      for (int s = 0; s < 2; ++s)
        glds16(bP[hf][s] + (size_t)t * 64, smem + 2 * ASZ + (t & 1) * 16384 + bD[hf][s]);
    }
  };

  // ---------- ds_read bases: frag(row r, kgroup g) at r*64 + (g^(r&7))*8 ----
  unsigned aBase = (unsigned)((wr * (BM / 2) + (lane & 31)) * 64);
  unsigned bBase = (unsigned)((wc * 64 + (lane & 31)) * 64);
  int kx[4];
#pragma unroll
  for (int ks = 0; ks < 4; ++ks)
    kx[ks] = ((2 * ks + (lane >> 5)) ^ (lane & 7)) * 8;

  f32x16 acc[MW][2];
#pragma unroll
  for (int m = 0; m < MW; ++m)
#pragma unroll
    for (int n = 0; n < 2; ++n)
#pragma unroll
      for (int j = 0; j < 16; ++j) acc[m][n][j] = 0.f;

  short8 aL0[MH][2], aL1[MH][2], aHH[MH][4], bL[2][2], bHi[2][2];

#define GUARD() if constexpr (GID == 0) { VMW4(); } else { VMW2(); }

  // ---------- prologue: A0, B0, A1; land A0,B0 ----------
  stA(0, 0); stA(0, 1); stB(0, 0); stB(0, 1); stA(1, 0); stA(1, 1);
  GUARD(); FEN(); BARX(); FEN();

  for (int it = 0; it < NT / 2; ++it) {
#pragma unroll
    for (int half = 0; half < 2; ++half) {
      int Tn = 2 * it + half;
      unsigned Ab = half ? (unsigned)ASZ : 0u;
      unsigned Bb = 2u * ASZ + (half ? 16384u : 0u);
      // ---- P0: aLo ks01, b ks01; stage B(Tn+1).h0 ----
#pragma unroll
      for (int m = 0; m < MH; ++m)
#pragma unroll
        for (int ks = 0; ks < 2; ++ks)
          aL0[m][ks] = *(const short8*)(smem + Ab + aBase + m * 2048 + kx[ks]);
#pragma unroll
      for (int n = 0; n < 2; ++n)
#pragma unroll
        for (int ks = 0; ks < 2; ++ks)
          bL[n][ks] = *(const short8*)(smem + Bb + bBase + n * 2048 + kx[ks]);
      stB(Tn + 1, 0);
      FEN(); BARX(); FEN();
      PRIO(1);
#pragma unroll
      for (int ks = 0; ks < 2; ++ks)
#pragma unroll
        for (int m = 0; m < MH; ++m)
#pragma unroll
          for (int n = 0; n < 2; ++n)
            acc[m][n] = __builtin_amdgcn_mfma_f32_32x32x16_bf16(
                aL0[m][ks], bL[n][ks], acc[m][n], 0, 0, 0);
      PRIO(0);
      FEN(); BARX(); FEN();
      // ---- P1: aLo ks23, b ks23; stage B(Tn+1).h1 ----
#pragma unroll
      for (int m = 0; m < MH; ++m)
#pragma unroll
        for (int ks = 0; ks < 2; ++ks)
          aL1[m][ks] = *(const short8*)(smem + Ab + aBase + m * 2048 + kx[2 + ks]);
#pragma unroll
      for (int n = 0; n < 2; ++n)
#pragma unroll
        for (int ks = 0; ks < 2; ++ks)
          bHi[n][ks] = *(const short8*)(smem + Bb + bBase + n * 2048 + kx[2 + ks]);
      stB(Tn + 1, 1);
      FEN(); BARX(); FEN();
      PRIO(1);
#pragma unroll
      for (int ks = 0; ks < 2; ++ks)
#pragma unroll
        for (int m = 0; m < MH; ++m)
#pragma unroll
          for (int n = 0; n < 2; ++n)
            acc[m][n] = __builtin_amdgcn_mfma_f32_32x32x16_bf16(
                aL1[m][ks], bHi[n][ks], acc[m][n], 0, 0, 0);
      PRIO(0);
      FEN(); BARX(); FEN();
      // ---- P2: aHi ks0-3; stage A(Tn+2).h0; MFMA hi x ks01 ----
#pragma unroll
      for (int m = 0; m < MH; ++m)
#pragma unroll
        for (int ks = 0; ks < 4; ++ks)
          aHH[m][ks] = *(const short8*)(smem + Ab + aBase + (MH + m) * 2048 + kx[ks]);
      stA(Tn + 2, 0);
      FEN(); BARX(); FEN();
      PRIO(1);
#pragma unroll
      for (int ks = 0; ks < 2; ++ks)
#pragma unroll
        for (int m = 0; m < MH; ++m)
#pragma unroll
          for (int n = 0; n < 2; ++n)
            acc[MH + m][n] = __builtin_amdgcn_mfma_f32_32x32x16_bf16(
                aHH[m][ks], bL[n][ks], acc[MH + m][n], 0, 0, 0);
      PRIO(0);
      LGKM0();           // aHH ks2-3 fully landed before h1-stage can issue
      FEN(); BARX(); FEN();
      // ---- P3: stage A(Tn+2).h1; MFMA hi x ks23; guard ----
      stA(Tn + 2, 1);
      FEN(); BARX(); FEN();
      PRIO(1);
#pragma unroll
      for (int ks = 0; ks < 2; ++ks)
#pragma unroll
        for (int m = 0; m < MH; ++m)
#pragma unroll
          for (int n = 0; n < 2; ++n)
            acc[MH + m][n] = __builtin_amdgcn_mfma_f32_32x32x16_bf16(
                aHH[m][2 + ks], bHi[n][ks], acc[MH + m][n], 0, 0, 0);
      PRIO(0);
      if (Tn + 2 < NT) { GUARD(); } else { VMW0(); }
      FEN(); BARX(); FEN();
    }
  }
#undef GUARD

  // ---------- epilogue (C/D: col=lane&31, row=(reg&3)+8*(reg>>2)+4*(lane>>5))
  int cc = lane & 31;
  int rhi = (lane >> 5) * 4;
  if (GID == 0) {
    int hcol = jb * 128 + wc * 32 + cc;
    float ba = bias[e * 2 * HID + hcol];
    float bbv = bias[e * 2 * HID + HID + hcol];
#pragma unroll
    for (int m = 0; m < MW; ++m)
#pragma unroll
      for (int reg = 0; reg < 16; ++reg) {
        int grow = row0 + wr * (BM / 2) + m * 32 + (reg & 3) + 8 * (reg >> 2) + rhi;
        if (grow < cntE) {
          float av = acc[m][0][reg] + ba;
          float bv = acc[m][1][reg] + bbv;
          float hv = av / (1.f + __expf(-av)) * bv;
          hb[(size_t)(base + grow) * HID + hcol] = f2bf(hv);
        }
      }
  } else {
    int col0 = jb * 256 + wc * 64;
    float bv0 = bias[e * DIM + col0 + cc];
    float bv1 = bias[e * DIM + col0 + 32 + cc];
#pragma unroll
    for (int m = 0; m < MW; ++m)
#pragma unroll
      for (int reg = 0; reg < 16; ++reg) {
        int grow = row0 + wr * (BM / 2) + m * 32 + (reg & 3) + 8 * (reg >> 2) + rhi;
        if (grow < cntE) {
          int tok = rows[base + grow];
          float g = rowg[base + grow];
          atomicAdd(&out[(size_t)tok * DIM + col0 + cc], g * (acc[m][0][reg] + bv0));
          atomicAdd(&out[(size_t)tok * DIM + col0 + 32 + cc], g * (acc[m][1][reg] + bv1));
        }
      }
  }
}

extern "C" void kernel_launch(void* const* d_in, const int* in_sizes, int n_in,
                              void* d_out, int out_size, void* d_ws, size_t ws_size,
                              hipStream_t stream) {
  (void)in_sizes; (void)n_in; (void)out_size;
  const float* x  = (const float*)d_in[0];
  const float* Wr = (const float*)d_in[1];
  const float* W1 = (const float*)d_in[2];
  const float* b1 = (const float*)d_in[3];
  const float* W2 = (const float*)d_in[4];
  const float* b2 = (const float*)d_in[5];
  float* out = (float*)d_out;
  char* ws = (char*)d_ws;

  const size_t o_xb   = 0;
  const size_t o_w1t  = o_xb   + (size_t)N_TOK * DIM * 2;
  const size_t o_w2t  = o_w1t  + (size_t)NEXP * 2 * HID * DIM * 2;
  const size_t o_hb   = o_w2t  + (size_t)NEXP * DIM * HID * 2;
  const size_t o_rows = o_hb   + (size_t)NK * HID * 2;
  const size_t o_rowg = o_rows + (size_t)NK * 4;
  const size_t o_te   = o_rowg + (size_t)NK * 4;
  const size_t o_tg   = o_te   + (size_t)NK * 4;
  const size_t o_offs = o_tg   + (size_t)NK * 4;
  const size_t o_t2   = o_offs + 64;
  const size_t o_t1   = o_t2   + 64;
  const size_t need   = o_t1   + 64;
  if (ws_size < need) return;

  unsigned short* xb  = (unsigned short*)(ws + o_xb);
  unsigned short* w1t = (unsigned short*)(ws + o_w1t);
  unsigned short* w2t = (unsigned short*)(ws + o_w2t);
  unsigned short* hb  = (unsigned short*)(ws + o_hb);
  int*   rows = (int*)(ws + o_rows);
  float* rowg = (float*)(ws + o_rowg);
  int*   te   = (int*)(ws + o_te);
  float* tg   = (float*)(ws + o_tg);
  int*   offs = (int*)(ws + o_offs);
  int*   tl256 = (int*)(ws + o_t2);
  int*   tl128 = (int*)(ws + o_t1);

  prep_k<<<16384, 256, 0, stream>>>(x, Wr, W1, W2, w1t, w2t, xb, te, tg, out);
  sortscan_k<<<1, 1024, 0, stream>>>(te, tg, offs, tl256, tl128, rows, rowg);
  moe_gemm32<0, 256><<<dim3(MAXT2, HID / 128), 512, 0, stream>>>(
      xb, w1t, b1, hb, nullptr, rows, rowg, offs, tl256);
  moe_gemm32<1, 128><<<dim3(MAXT1, DIM / 256), 512, 0, stream>>>(
      hb, w2t, b2, nullptr, out, rows, rowg, offs, tl128);
}

// Round 12
// 413.530 us; speedup vs baseline: 1.0652x; 1.0652x over previous
//
#include <hip/hip_runtime.h>

// MoE top-2/8: routed bf16-MFMA grouped GEMMs.
// R12: R8 kernels (16x16x32, BK=64, gemm1 BM=256 / gemm2 BM=128) + grid
// transposed so jb (N-tile) is the fast axis: consecutive blocks share the
// A-panel and walk one expert's row-tiles consecutively -> L2 reuse
// (FETCH 350MB -> ~unique-data level).

#define N_TOK 8192
#define DIM   1024
#define HID   2048
#define NEXP  8
#define NK    (N_TOK * 2)
#define MAXT2 72    // max 256-row tiles (64 full + 8 partial)
#define MAXT1 136   // max 128-row tiles (128 full + 8 partial)

typedef __attribute__((ext_vector_type(8))) short short8;
typedef __attribute__((ext_vector_type(4))) float f32x4;

#define BARX() __builtin_amdgcn_s_barrier()
#define FEN()  asm volatile("" ::: "memory")
#define VMW4() asm volatile("s_waitcnt vmcnt(4)" ::: "memory")
#define VMW2() asm volatile("s_waitcnt vmcnt(2)" ::: "memory")
#define VMW0() asm volatile("s_waitcnt vmcnt(0)" ::: "memory")
#define PRIO(p) __builtin_amdgcn_s_setprio(p)

static __device__ __forceinline__ unsigned short f2bf(float f) {
  unsigned int u = __float_as_uint(f);
  u += 0x7fffu + ((u >> 16) & 1u);
  return (unsigned short)(u >> 16);
}

static __device__ __forceinline__ void glds16(const void* g, void* l) {
  __builtin_amdgcn_global_load_lds(
      (const __attribute__((address_space(1))) unsigned int*)g,
      (__attribute__((address_space(3))) unsigned int*)l, 16, 0, 0);
}

// ================= prep: W1^T || W2^T || router || zero(out) ================
__device__ __forceinline__ void transpose_tile(const float* __restrict__ s,
                                               unsigned short* __restrict__ d,
                                               int R, int C, int c0, int r0,
                                               unsigned short (*tT)[68]) {
  int tid = threadIdx.x;
  int c = tid & 63, rq = tid >> 6;
#pragma unroll
  for (int q = 0; q < 4; ++q) {
    int rb = q * 16 + rq * 4;
    ushort4 v;
    v.x = f2bf(s[(size_t)(r0 + rb + 0) * C + c0 + c]);
    v.y = f2bf(s[(size_t)(r0 + rb + 1) * C + c0 + c]);
    v.z = f2bf(s[(size_t)(r0 + rb + 2) * C + c0 + c]);
    v.w = f2bf(s[(size_t)(r0 + rb + 3) * C + c0 + c]);
    *(ushort4*)&tT[c][rb] = v;
  }
  __syncthreads();
#pragma unroll
  for (int it = 0; it < 4; ++it) {
    int idx = it * 256 + tid;
    int cc = idx >> 4;
    int r4 = (idx & 15) * 4;
    *(ushort4*)(d + (size_t)(c0 + cc) * R + r0 + r4) = *(const ushort4*)&tT[cc][r4];
  }
}

__global__ __launch_bounds__(256) void prep_k(
    const float* __restrict__ x, const float* __restrict__ Wr,
    const float* __restrict__ W1, const float* __restrict__ W2,
    unsigned short* __restrict__ w1t, unsigned short* __restrict__ w2t,
    unsigned short* __restrict__ xb, int* __restrict__ te,
    float* __restrict__ tg, float* __restrict__ out) {
  __shared__ unsigned short tT[64][68];
  int bid = blockIdx.x;
  if (bid < 8192) {                       // W1 transpose
    int z = bid >> 10, rem = bid & 1023;
    int c0 = (rem & 63) * 64, r0 = (rem >> 6) * 64;
    transpose_tile(W1 + (size_t)z * DIM * 2 * HID,
                   w1t + (size_t)z * DIM * 2 * HID, DIM, 2 * HID, c0, r0, tT);
  } else if (bid < 12288) {               // W2 transpose
    int b2 = bid - 8192;
    int z = b2 >> 9, rem = b2 & 511;
    int c0 = (rem & 15) * 64, r0 = (rem >> 4) * 64;
    transpose_tile(W2 + (size_t)z * HID * DIM,
                   w2t + (size_t)z * HID * DIM, HID, DIM, c0, r0, tT);
  } else if (bid < 14336) {               // router (4 tokens, 1 wave each)
    int n = (bid - 12288) * 4 + (threadIdx.x >> 6);
    int lane = threadIdx.x & 63;
    float z[8];
#pragma unroll
    for (int e = 0; e < 8; ++e) z[e] = 0.f;
    const float* xr = x + (size_t)n * DIM;
    unsigned short* xbr = xb + (size_t)n * DIM;
#pragma unroll 4
    for (int i = 0; i < DIM / 64; ++i) {
      int d = lane + i * 64;
      float xv = xr[d];
      xbr[d] = f2bf(xv);
      float4 w0 = *(const float4*)(Wr + (size_t)d * 8);
      float4 w1 = *(const float4*)(Wr + (size_t)d * 8 + 4);
      z[0] += xv * w0.x; z[1] += xv * w0.y; z[2] += xv * w0.z; z[3] += xv * w0.w;
      z[4] += xv * w1.x; z[5] += xv * w1.y; z[6] += xv * w1.z; z[7] += xv * w1.w;
    }
    for (int off = 32; off; off >>= 1)
#pragma unroll
      for (int e = 0; e < 8; ++e) z[e] += __shfl_down(z[e], off);
    if (lane == 0) {
      int e0 = 0; float v0 = z[0];
#pragma unroll
      for (int e = 1; e < 8; ++e) if (z[e] > v0) { v0 = z[e]; e0 = e; }
      int e1 = -1; float v1 = -3.4e38f;
#pragma unroll
      for (int e = 0; e < 8; ++e) if (e != e0 && z[e] > v1) { v1 = z[e]; e1 = e; }
      float r = expf(v1 - v0);
      float s0 = 1.f / (1.f + r);
      te[n * 2] = e0; te[n * 2 + 1] = e1;
      tg[n * 2] = s0; tg[n * 2 + 1] = r * s0;
    }
  } else {                                // zero out
    int t = bid - 14336;
    float4* o4 = (float4*)out;
    int idx = t * 256 + threadIdx.x;
#pragma unroll
    for (int i = 0; i < 4; ++i) o4[idx + i * 524288] = (float4){0.f, 0.f, 0.f, 0.f};
  }
}

// ===== sortscan: one block; histogram -> offs/tl256/tl128, scatter ==========
__global__ __launch_bounds__(1024) void sortscan_k(
    const int* __restrict__ te, const float* __restrict__ tg,
    int* __restrict__ offs, int* __restrict__ tl256, int* __restrict__ tl128,
    int* __restrict__ rows, float* __restrict__ rowg) {
  __shared__ int hist[8];
  __shared__ int curs[8];
  int tid = threadIdx.x;
  if (tid < 8) hist[tid] = 0;
  __syncthreads();
  for (int i = tid; i < NK; i += 1024) atomicAdd(&hist[te[i]], 1);
  __syncthreads();
  if (tid == 0) {
    int o = 0, t2 = 0, t1 = 0;
    offs[0] = 0; tl256[0] = 0; tl128[0] = 0;
    for (int e = 0; e < NEXP; ++e) {
      curs[e] = o;
      o += hist[e];
      offs[e + 1] = o;
      t2 += (hist[e] + 255) >> 8;
      tl256[e + 1] = t2;
      t1 += (hist[e] + 127) >> 7;
      tl128[e + 1] = t1;
    }
  }
  __syncthreads();
  for (int i = tid; i < NK; i += 1024) {
    int e = te[i];
    int pos = atomicAdd(&curs[e], 1);
    rows[pos] = i >> 1;
    rowg[pos] = tg[i];
  }
}

// ============ 8-phase BMx256 grouped GEMM (per-phase interleave) ============
// jb (N-tile) = blockIdx.x (fast axis, L2 reuse); bt = blockIdx.y.
template <int GID, int BM>
__global__ __launch_bounds__(512, 2) void moe_gemm8p(
    const unsigned short* __restrict__ Asrc,
    const unsigned short* __restrict__ Wt,
    const float* __restrict__ bias,
    unsigned short* __restrict__ hb,
    float* __restrict__ out,
    const int* __restrict__ rows,
    const float* __restrict__ rowg,
    const int* __restrict__ offs,
    const int* __restrict__ tl) {
  constexpr int KD = (GID == 0) ? DIM : HID;
  constexpr int NT = KD / 64;
  constexpr int MF = BM / 32;          // m-frags per wave
  constexpr int HBIT = BM / 4;         // A-half row-bit value
  constexpr int AG = BM / 128;         // glds per A-half per thread
  constexpr int ASZ = BM * 64;         // A slab elements
  __shared__ unsigned short smem[2 * ASZ + 2 * 16384];

  int bt = blockIdx.y;
  if (bt >= tl[NEXP]) return;
  int e = 0;
  while (e < NEXP - 1 && bt >= tl[e + 1]) ++e;
  int rt = bt - tl[e];
  int base = offs[e];
  int cntE = offs[e + 1] - base;
  int row0 = rt * BM;
  int jb = blockIdx.x;

  int tid = threadIdx.x, lane = tid & 63, w = tid >> 6;
  int wr = w >> 2, wc = w & 3;

  // ---------- staging sources/dsts: 2 halves x AG/2 slots ----------
  int g8 = (((lane & 7) ^ ((lane >> 3) & 7)) * 8);  // pre-swizzled k-group
  const unsigned short* aP[2][AG];
  const unsigned short* bP[2][2];
  int aD[2][AG], bD[2][2];
#pragma unroll
  for (int hf = 0; hf < 2; ++hf) {
#pragma unroll
    for (int s = 0; s < AG; ++s) {
      int q0 = w * (BM / 16) + s * 8;
      int rbA = (q0 < HBIT ? q0 : q0 + HBIT) + hf * HBIT;
      int rA = rbA + (lane >> 3);
      int rr = row0 + rA; rr = rr < cntE ? rr : cntE - 1;
      if (GID == 0) {
        int tok = rows[base + rr];
        aP[hf][s] = Asrc + (size_t)tok * DIM + g8;
      } else {
        aP[hf][s] = Asrc + (size_t)(base + rr) * HID + g8;
      }
      aD[hf][s] = rbA * 64;
    }
#pragma unroll
    for (int s = 0; s < 2; ++s) {
      int q0 = w * 16 + s * 8;
      int rB = hf * 128 + q0 + (lane >> 3);
      if (GID == 0) {
        int j0h = jb * 128;
        int hcol = j0h + (rB >> 5) * 16 + (rB & 15);
        int w1row = hcol + ((rB >> 4) & 1) * HID;   // +HID for b-half of swiGLU
        bP[hf][s] = Wt + ((size_t)e * 2 * HID + w1row) * DIM + g8;
      } else {
        int j0 = jb * 256;
        bP[hf][s] = Wt + ((size_t)e * DIM + (j0 + rB)) * HID + g8;
      }
      bD[hf][s] = (hf * 128 + q0) * 64;
    }
  }

  auto stA = [&](int t, int hf) {
    if (t < NT) {
#pragma unroll
      for (int s = 0; s < AG; ++s)
        glds16(aP[hf][s] + (size_t)t * 64, smem + (t & 1) * ASZ + aD[hf][s]);
    }
  };
  auto stB = [&](int t, int hf) {
    if (t < NT) {
#pragma unroll
      for (int s = 0; s < 2; ++s)
        glds16(bP[hf][s] + (size_t)t * 64, smem + 2 * ASZ + (t & 1) * 16384 + bD[hf][s]);
    }
  };

  // ---------- ds_read offsets (elements), swizzle matches staging ----------
  int arow = wr * (BM / 2) + (lane & 15);
  int brow = wc * 64 + (lane & 15);
  int kg = lane >> 4, sx = lane & 7;
  unsigned aoffs[2] = {(unsigned)(arow * 64 + ((kg ^ sx) * 8)),
                       (unsigned)(arow * 64 + (((4 + kg) ^ sx) * 8))};
  unsigned boffs[2] = {(unsigned)(brow * 64 + ((kg ^ sx) * 8)),
                       (unsigned)(brow * 64 + (((4 + kg) ^ sx) * 8))};

  f32x4 acc[MF][4];
#pragma unroll
  for (int m = 0; m < MF; ++m)
#pragma unroll
    for (int n = 0; n < 4; ++n) acc[m][n] = (f32x4){0.f, 0.f, 0.f, 0.f};

  short8 a[2][MF / 2], b[2][4];

#define MFMA_Q(MB, NB)                                                        \
  PRIO(1);                                                                    \
  _Pragma("unroll") for (int ks = 0; ks < 2; ++ks)                            \
  _Pragma("unroll") for (int m = 0; m < MF / 2; ++m)                          \
  _Pragma("unroll") for (int n = 0; n < 2; ++n)                               \
    acc[(MB) + m][(NB) + n] = __builtin_amdgcn_mfma_f32_16x16x32_bf16(        \
        a[ks][m], b[ks][(NB) + n], acc[(MB) + m][(NB) + n], 0, 0, 0);         \
  PRIO(0)

#define GUARD_CNT()                                                           \
  if constexpr (BM == 256) { VMW4(); } else { VMW2(); }

  // ---------- prologue: A0, B0, A1 halves; land A0,B0 ----------
  stA(0, 0); stA(0, 1); stB(0, 0); stB(0, 1); stA(1, 0); stA(1, 1);
  GUARD_CNT(); FEN(); BARX(); FEN();

  for (int it = 0; it < NT / 2; ++it) {
    int T = 2 * it;
    bool notlast = (it < NT / 2 - 1);
#pragma unroll
    for (int half = 0; half < 2; ++half) {
      unsigned Ab = half ? (unsigned)ASZ : 0u;
      unsigned Bb = 2u * ASZ + (half ? 16384u : 0u);
      int Tn = T + half;
      // ---- P0/P4: a[lo half], b[v0]; stage B(Tn+1).h0 ----
#pragma unroll
      for (int ks = 0; ks < 2; ++ks) {
#pragma unroll
        for (int m = 0; m < MF / 2; ++m)
          a[ks][m] = *(const short8*)(smem + Ab + aoffs[ks] + m * 1024);
#pragma unroll
        for (int n = 0; n < 2; ++n)
          b[ks][n] = *(const short8*)(smem + Bb + boffs[ks] + n * 1024);
      }
      stB(Tn + 1, 0);
      FEN(); BARX(); FEN();
      MFMA_Q(0, 0);
      FEN(); BARX(); FEN();
      // ---- P1/P5: b[v1]; stage B(Tn+1).h1 ----
#pragma unroll
      for (int ks = 0; ks < 2; ++ks)
#pragma unroll
        for (int n = 2; n < 4; ++n)
          b[ks][n] = *(const short8*)(smem + Bb + boffs[ks] + n * 1024);
      stB(Tn + 1, 1);
      FEN(); BARX(); FEN();
      MFMA_Q(0, 2);
      FEN(); BARX(); FEN();
      // ---- P2/P6: a[hi half]; stage A(Tn+2).q0 ----
#pragma unroll
      for (int ks = 0; ks < 2; ++ks)
#pragma unroll
        for (int m = 0; m < MF / 2; ++m)
          a[ks][m] = *(const short8*)(smem + Ab + aoffs[ks] + (MF / 2 + m) * 1024);
      stA(Tn + 2, 0);
      FEN(); BARX(); FEN();
      MFMA_Q(MF / 2, 2);
      FEN(); BARX(); FEN();
      // ---- P3/P7: stage A(Tn+2).q1; MFMA; guard-before-barrier ----
      stA(Tn + 2, 1);
      FEN(); BARX(); FEN();
      MFMA_Q(MF / 2, 0);
      if (half == 0) {
        if (notlast) { GUARD_CNT(); } else { VMW0(); }
      } else {
        GUARD_CNT();
      }
      FEN(); BARX(); FEN();
    }
  }
#undef MFMA_Q
#undef GUARD_CNT

  // ---------- epilogue ----------
  int rowl = lane >> 4, coll = lane & 15;
  if (GID == 0) {
    int j0h = jb * 128;
#pragma unroll
    for (int pair = 0; pair < 2; ++pair) {
      int hcol = j0h + (2 * wc + pair) * 16 + coll;
      float ba = bias[e * 2 * HID + hcol];
      float bb = bias[e * 2 * HID + HID + hcol];
#pragma unroll
      for (int m = 0; m < MF; ++m)
#pragma unroll
        for (int j = 0; j < 4; ++j) {
          int grow = row0 + wr * (BM / 2) + m * 16 + rowl * 4 + j;
          if (grow < cntE) {
            float av = acc[m][2 * pair][j] + ba;
            float bv = acc[m][2 * pair + 1][j] + bb;
            float hv = av / (1.f + __expf(-av)) * bv;
            hb[(size_t)(base + grow) * HID + hcol] = f2bf(hv);
          }
        }
    }
  } else {
    int j0 = jb * 256;
    float bv[4];
#pragma unroll
    for (int n = 0; n < 4; ++n) bv[n] = bias[e * DIM + j0 + wc * 64 + n * 16 + coll];
#pragma unroll
    for (int m = 0; m < MF; ++m)
#pragma unroll
      for (int j = 0; j < 4; ++j) {
        int grow = row0 + wr * (BM / 2) + m * 16 + rowl * 4 + j;
        if (grow < cntE) {
          int tok = rows[base + grow];
          float g = rowg[base + grow];
#pragma unroll
          for (int n = 0; n < 4; ++n) {
            int col = j0 + wc * 64 + n * 16 + coll;
            atomicAdd(&out[(size_t)tok * DIM + col], g * (acc[m][n][j] + bv[n]));
          }
        }
      }
  }
}

extern "C" void kernel_launch(void* const* d_in, const int* in_sizes, int n_in,
                              void* d_out, int out_size, void* d_ws, size_t ws_size,
                              hipStream_t stream) {
  (void)in_sizes; (void)n_in; (void)out_size;
  const float* x  = (const float*)d_in[0];
  const float* Wr = (const float*)d_in[1];
  const float* W1 = (const float*)d_in[2];
  const float* b1 = (const float*)d_in[3];
  const float* W2 = (const float*)d_in[4];
  const float* b2 = (const float*)d_in[5];
  float* out = (float*)d_out;
  char* ws = (char*)d_ws;

  const size_t o_xb   = 0;
  const size_t o_w1t  = o_xb   + (size_t)N_TOK * DIM * 2;
  const size_t o_w2t  = o_w1t  + (size_t)NEXP * 2 * HID * DIM * 2;
  const size_t o_hb   = o_w2t  + (size_t)NEXP * DIM * HID * 2;
  const size_t o_rows = o_hb   + (size_t)NK * HID * 2;
  const size_t o_rowg = o_rows + (size_t)NK * 4;
  const size_t o_te   = o_rowg + (size_t)NK * 4;
  const size_t o_tg   = o_te   + (size_t)NK * 4;
  const size_t o_offs = o_tg   + (size_t)NK * 4;
  const size_t o_t2   = o_offs + 64;
  const size_t o_t1   = o_t2   + 64;
  const size_t need   = o_t1   + 64;
  if (ws_size < need) return;

  unsigned short* xb  = (unsigned short*)(ws + o_xb);
  unsigned short* w1t = (unsigned short*)(ws + o_w1t);
  unsigned short* w2t = (unsigned short*)(ws + o_w2t);
  unsigned short* hb  = (unsigned short*)(ws + o_hb);
  int*   rows = (int*)(ws + o_rows);
  float* rowg = (float*)(ws + o_rowg);
  int*   te   = (int*)(ws + o_te);
  float* tg   = (float*)(ws + o_tg);
  int*   offs = (int*)(ws + o_offs);
  int*   tl256 = (int*)(ws + o_t2);
  int*   tl128 = (int*)(ws + o_t1);

  prep_k<<<16384, 256, 0, stream>>>(x, Wr, W1, W2, w1t, w2t, xb, te, tg, out);
  sortscan_k<<<1, 1024, 0, stream>>>(te, tg, offs, tl256, tl128, rows, rowg);
  moe_gemm8p<0, 256><<<dim3(HID / 128, MAXT2), 512, 0, stream>>>(
      xb, w1t, b1, hb, nullptr, rows, rowg, offs, tl256);
  moe_gemm8p<1, 128><<<dim3(DIM / 256, MAXT1), 512, 0, stream>>>(
      hb, w2t, b2, nullptr, out, rows, rowg, offs, tl128);
}

// Round 13
// 395.198 us; speedup vs baseline: 1.1146x; 1.0464x over previous
//
#include <hip/hip_runtime.h>

// MoE top-2/8: routed bf16-MFMA grouped GEMMs.
// R13: R12 GEMMs unchanged; W2-transpose + out-zeroing folded into gemm1's
// grid as tail blocks (bt>=72) so they fill the 5th-round idle CUs and leave
// prep = W1T + router only. 4 launches total.

#define N_TOK 8192
#define DIM   1024
#define HID   2048
#define NEXP  8
#define NK    (N_TOK * 2)
#define MAXT2 72    // max 256-row tiles (64 full + 8 partial)
#define MAXT1 136   // max 128-row tiles (128 full + 8 partial)
#define AUXY  216   // gemm1 grid y: [0,72) tiles, [72,200) W2T, [200,216) zero

typedef __attribute__((ext_vector_type(8))) short short8;
typedef __attribute__((ext_vector_type(4))) float f32x4;

#define BARX() __builtin_amdgcn_s_barrier()
#define FEN()  asm volatile("" ::: "memory")
#define VMW4() asm volatile("s_waitcnt vmcnt(4)" ::: "memory")
#define VMW2() asm volatile("s_waitcnt vmcnt(2)" ::: "memory")
#define VMW0() asm volatile("s_waitcnt vmcnt(0)" ::: "memory")
#define PRIO(p) __builtin_amdgcn_s_setprio(p)

static __device__ __forceinline__ unsigned short f2bf(float f) {
  unsigned int u = __float_as_uint(f);
  u += 0x7fffu + ((u >> 16) & 1u);
  return (unsigned short)(u >> 16);
}

static __device__ __forceinline__ void glds16(const void* g, void* l) {
  __builtin_amdgcn_global_load_lds(
      (const __attribute__((address_space(1))) unsigned int*)g,
      (__attribute__((address_space(3))) unsigned int*)l, 16, 0, 0);
}

// ---- 64x64 transpose-convert tile, 256-thread version (prep/W1T) ----
__device__ __forceinline__ void transpose_tile(const float* __restrict__ s,
                                               unsigned short* __restrict__ d,
                                               int R, int C, int c0, int r0,
                                               unsigned short (*tT)[68]) {
  int tid = threadIdx.x;
  int c = tid & 63, rq = tid >> 6;
#pragma unroll
  for (int q = 0; q < 4; ++q) {
    int rb = q * 16 + rq * 4;
    ushort4 v;
    v.x = f2bf(s[(size_t)(r0 + rb + 0) * C + c0 + c]);
    v.y = f2bf(s[(size_t)(r0 + rb + 1) * C + c0 + c]);
    v.z = f2bf(s[(size_t)(r0 + rb + 2) * C + c0 + c]);
    v.w = f2bf(s[(size_t)(r0 + rb + 3) * C + c0 + c]);
    *(ushort4*)&tT[c][rb] = v;
  }
  __syncthreads();
#pragma unroll
  for (int it = 0; it < 4; ++it) {
    int idx = it * 256 + tid;
    int cc = idx >> 4;
    int r4 = (idx & 15) * 4;
    *(ushort4*)(d + (size_t)(c0 + cc) * R + r0 + r4) = *(const ushort4*)&tT[cc][r4];
  }
}

// ---- 64x64 transpose-convert tile, 512-thread version (gemm1 aux/W2T) ----
__device__ __forceinline__ void transpose_tile512(const float* __restrict__ s,
                                                  unsigned short* __restrict__ d,
                                                  int R, int C, int c0, int r0,
                                                  unsigned short (*tT)[68]) {
  int tid = threadIdx.x;           // 0..511
  int c = tid & 63, rq = tid >> 6; // 0..7
#pragma unroll
  for (int q = 0; q < 2; ++q) {
    int rb = q * 32 + rq * 4;
    ushort4 v;
    v.x = f2bf(s[(size_t)(r0 + rb + 0) * C + c0 + c]);
    v.y = f2bf(s[(size_t)(r0 + rb + 1) * C + c0 + c]);
    v.z = f2bf(s[(size_t)(r0 + rb + 2) * C + c0 + c]);
    v.w = f2bf(s[(size_t)(r0 + rb + 3) * C + c0 + c]);
    *(ushort4*)&tT[c][rb] = v;
  }
  __syncthreads();
#pragma unroll
  for (int it = 0; it < 2; ++it) {
    int idx = it * 512 + tid;
    int cc = idx >> 4;
    int r4 = (idx & 15) * 4;
    *(ushort4*)(d + (size_t)(c0 + cc) * R + r0 + r4) = *(const ushort4*)&tT[cc][r4];
  }
}

// ================= prep: W1^T || router (+x->bf16) ================
//   [0,8192)      W1 transpose tiles
//   [8192,10240)  router (4 tokens/block)
__global__ __launch_bounds__(256) void prep_k(
    const float* __restrict__ x, const float* __restrict__ Wr,
    const float* __restrict__ W1,
    unsigned short* __restrict__ w1t,
    unsigned short* __restrict__ xb, int* __restrict__ te,
    float* __restrict__ tg) {
  __shared__ unsigned short tT[64][68];
  int bid = blockIdx.x;
  if (bid < 8192) {                       // W1 transpose
    int z = bid >> 10, rem = bid & 1023;
    int c0 = (rem & 63) * 64, r0 = (rem >> 6) * 64;
    transpose_tile(W1 + (size_t)z * DIM * 2 * HID,
                   w1t + (size_t)z * DIM * 2 * HID, DIM, 2 * HID, c0, r0, tT);
  } else {                                // router (4 tokens, 1 wave each)
    int n = (bid - 8192) * 4 + (threadIdx.x >> 6);
    int lane = threadIdx.x & 63;
    float z[8];
#pragma unroll
    for (int e = 0; e < 8; ++e) z[e] = 0.f;
    const float* xr = x + (size_t)n * DIM;
    unsigned short* xbr = xb + (size_t)n * DIM;
#pragma unroll 4
    for (int i = 0; i < DIM / 64; ++i) {
      int d = lane + i * 64;
      float xv = xr[d];
      xbr[d] = f2bf(xv);
      float4 w0 = *(const float4*)(Wr + (size_t)d * 8);
      float4 w1 = *(const float4*)(Wr + (size_t)d * 8 + 4);
      z[0] += xv * w0.x; z[1] += xv * w0.y; z[2] += xv * w0.z; z[3] += xv * w0.w;
      z[4] += xv * w1.x; z[5] += xv * w1.y; z[6] += xv * w1.z; z[7] += xv * w1.w;
    }
    for (int off = 32; off; off >>= 1)
#pragma unroll
      for (int e = 0; e < 8; ++e) z[e] += __shfl_down(z[e], off);
    if (lane == 0) {
      int e0 = 0; float v0 = z[0];
#pragma unroll
      for (int e = 1; e < 8; ++e) if (z[e] > v0) { v0 = z[e]; e0 = e; }
      int e1 = -1; float v1 = -3.4e38f;
#pragma unroll
      for (int e = 0; e < 8; ++e) if (e != e0 && z[e] > v1) { v1 = z[e]; e1 = e; }
      float r = expf(v1 - v0);
      float s0 = 1.f / (1.f + r);
      te[n * 2] = e0; te[n * 2 + 1] = e1;
      tg[n * 2] = s0; tg[n * 2 + 1] = r * s0;
    }
  }
}

// ===== sortscan: one block; histogram -> offs/tl256/tl128, scatter ==========
__global__ __launch_bounds__(1024) void sortscan_k(
    const int* __restrict__ te, const float* __restrict__ tg,
    int* __restrict__ offs, int* __restrict__ tl256, int* __restrict__ tl128,
    int* __restrict__ rows, float* __restrict__ rowg) {
  __shared__ int hist[8];
  __shared__ int curs[8];
  int tid = threadIdx.x;
  if (tid < 8) hist[tid] = 0;
  __syncthreads();
  for (int i = tid; i < NK; i += 1024) atomicAdd(&hist[te[i]], 1);
  __syncthreads();
  if (tid == 0) {
    int o = 0, t2 = 0, t1 = 0;
    offs[0] = 0; tl256[0] = 0; tl128[0] = 0;
    for (int e = 0; e < NEXP; ++e) {
      curs[e] = o;
      o += hist[e];
      offs[e + 1] = o;
      t2 += (hist[e] + 255) >> 8;
      tl256[e + 1] = t2;
      t1 += (hist[e] + 127) >> 7;
      tl128[e + 1] = t1;
    }
  }
  __syncthreads();
  for (int i = tid; i < NK; i += 1024) {
    int e = te[i];
    int pos = atomicAdd(&curs[e], 1);
    rows[pos] = i >> 1;
    rowg[pos] = tg[i];
  }
}

// ============ 8-phase BMx256 grouped GEMM (per-phase interleave) ============
// jb (N-tile) = blockIdx.x (fast axis, L2 reuse); bt = blockIdx.y.
// GID=0 extra bt rows: [72,200) W2-transpose (2 tiles/block), [200,216)
// zero-out of `out` — dispatched after the real tiles -> fill tail round.
template <int GID, int BM>
__global__ __launch_bounds__(512, 2) void moe_gemm8p(
    const unsigned short* __restrict__ Asrc,
    const unsigned short* __restrict__ Wt,
    const float* __restrict__ bias,
    unsigned short* __restrict__ hb,
    float* __restrict__ out,
    const int* __restrict__ rows,
    const float* __restrict__ rowg,
    const int* __restrict__ offs,
    const int* __restrict__ tl,
    const float* __restrict__ W2f,       // GID0 aux: W2 fp32 src
    unsigned short* __restrict__ w2td,   // GID0 aux: w2t dst
    float* __restrict__ outz) {          // GID0 aux: out to zero
  constexpr int KD = (GID == 0) ? DIM : HID;
  constexpr int NT = KD / 64;
  constexpr int MF = BM / 32;          // m-frags per wave
  constexpr int HBIT = BM / 4;         // A-half row-bit value
  constexpr int AG = BM / 128;         // glds per A-half per thread
  constexpr int ASZ = BM * 64;         // A slab elements
  __shared__ unsigned short smem[2 * ASZ + 2 * 16384];

  int bt = blockIdx.y;
  if (GID == 0 && bt >= MAXT2) {
    // ---------- auxiliary tail blocks ----------
    unsigned short (*tT)[68] = (unsigned short (*)[68])smem;
    if (bt < 200) {
      int base_t = ((bt - MAXT2) * 16 + (int)blockIdx.x) * 2;  // 0..4094
#pragma unroll
      for (int k = 0; k < 2; ++k) {
        if (k) __syncthreads();
        int t = base_t + k;
        int z = t >> 9, rem = t & 511;
        int c0 = (rem & 15) * 64, r0 = (rem >> 4) * 64;
        transpose_tile512(W2f + (size_t)z * HID * DIM,
                          w2td + (size_t)z * HID * DIM, HID, DIM, c0, r0, tT);
      }
    } else {
      int t = (bt - 200) * 16 + (int)blockIdx.x;   // 0..255
      float4* o4 = (float4*)outz;
      int idx = t * 512 + threadIdx.x;
#pragma unroll
      for (int i = 0; i < 16; ++i) o4[idx + i * 131072] = (float4){0.f, 0.f, 0.f, 0.f};
    }
    return;
  }
  if (bt >= tl[NEXP]) return;
  int e = 0;
  while (e < NEXP - 1 && bt >= tl[e + 1]) ++e;
  int rt = bt - tl[e];
  int base = offs[e];
  int cntE = offs[e + 1] - base;
  int row0 = rt * BM;
  int jb = blockIdx.x;

  int tid = threadIdx.x, lane = tid & 63, w = tid >> 6;
  int wr = w >> 2, wc = w & 3;

  // ---------- staging sources/dsts: 2 halves x AG/2 slots ----------
  int g8 = (((lane & 7) ^ ((lane >> 3) & 7)) * 8);  // pre-swizzled k-group
  const unsigned short* aP[2][AG];
  const unsigned short* bP[2][2];
  int aD[2][AG], bD[2][2];
#pragma unroll
  for (int hf = 0; hf < 2; ++hf) {
#pragma unroll
    for (int s = 0; s < AG; ++s) {
      int q0 = w * (BM / 16) + s * 8;
      int rbA = (q0 < HBIT ? q0 : q0 + HBIT) + hf * HBIT;
      int rA = rbA + (lane >> 3);
      int rr = row0 + rA; rr = rr < cntE ? rr : cntE - 1;
      if (GID == 0) {
        int tok = rows[base + rr];
        aP[hf][s] = Asrc + (size_t)tok * DIM + g8;
      } else {
        aP[hf][s] = Asrc + (size_t)(base + rr) * HID + g8;
      }
      aD[hf][s] = rbA * 64;
    }
#pragma unroll
    for (int s = 0; s < 2; ++s) {
      int q0 = w * 16 + s * 8;
      int rB = hf * 128 + q0 + (lane >> 3);
      if (GID == 0) {
        int j0h = jb * 128;
        int hcol = j0h + (rB >> 5) * 16 + (rB & 15);
        int w1row = hcol + ((rB >> 4) & 1) * HID;   // +HID for b-half of swiGLU
        bP[hf][s] = Wt + ((size_t)e * 2 * HID + w1row) * DIM + g8;
      } else {
        int j0 = jb * 256;
        bP[hf][s] = Wt + ((size_t)e * DIM + (j0 + rB)) * HID + g8;
      }
      bD[hf][s] = (hf * 128 + q0) * 64;
    }
  }

  auto stA = [&](int t, int hf) {
    if (t < NT) {
#pragma unroll
      for (int s = 0; s < AG; ++s)
        glds16(aP[hf][s] + (size_t)t * 64, smem + (t & 1) * ASZ + aD[hf][s]);
    }
  };
  auto stB = [&](int t, int hf) {
    if (t < NT) {
#pragma unroll
      for (int s = 0; s < 2; ++s)
        glds16(bP[hf][s] + (size_t)t * 64, smem + 2 * ASZ + (t & 1) * 16384 + bD[hf][s]);
    }
  };

  // ---------- ds_read offsets (elements), swizzle matches staging ----------
  int arow = wr * (BM / 2) + (lane & 15);
  int brow = wc * 64 + (lane & 15);
  int kg = lane >> 4, sx = lane & 7;
  unsigned aoffs[2] = {(unsigned)(arow * 64 + ((kg ^ sx) * 8)),
                       (unsigned)(arow * 64 + (((4 + kg) ^ sx) * 8))};
  unsigned boffs[2] = {(unsigned)(brow * 64 + ((kg ^ sx) * 8)),
                       (unsigned)(brow * 64 + (((4 + kg) ^ sx) * 8))};

  f32x4 acc[MF][4];
#pragma unroll
  for (int m = 0; m < MF; ++m)
#pragma unroll
    for (int n = 0; n < 4; ++n) acc[m][n] = (f32x4){0.f, 0.f, 0.f, 0.f};

  short8 a[2][MF / 2], b[2][4];

#define MFMA_Q(MB, NB)                                                        \
  PRIO(1);                                                                    \
  _Pragma("unroll") for (int ks = 0; ks < 2; ++ks)                            \
  _Pragma("unroll") for (int m = 0; m < MF / 2; ++m)                          \
  _Pragma("unroll") for (int n = 0; n < 2; ++n)                               \
    acc[(MB) + m][(NB) + n] = __builtin_amdgcn_mfma_f32_16x16x32_bf16(        \
        a[ks][m], b[ks][(NB) + n], acc[(MB) + m][(NB) + n], 0, 0, 0);         \
  PRIO(0)

#define GUARD_CNT()                                                           \
  if constexpr (BM == 256) { VMW4(); } else { VMW2(); }

  // ---------- prologue: A0, B0, A1 halves; land A0,B0 ----------
  stA(0, 0); stA(0, 1); stB(0, 0); stB(0, 1); stA(1, 0); stA(1, 1);
  GUARD_CNT(); FEN(); BARX(); FEN();

  for (int it = 0; it < NT / 2; ++it) {
    int T = 2 * it;
    bool notlast = (it < NT / 2 - 1);
#pragma unroll
    for (int half = 0; half < 2; ++half) {
      unsigned Ab = half ? (unsigned)ASZ : 0u;
      unsigned Bb = 2u * ASZ + (half ? 16384u : 0u);
      int Tn = T + half;
      // ---- P0/P4: a[lo half], b[v0]; stage B(Tn+1).h0 ----
#pragma unroll
      for (int ks = 0; ks < 2; ++ks) {
#pragma unroll
        for (int m = 0; m < MF / 2; ++m)
          a[ks][m] = *(const short8*)(smem + Ab + aoffs[ks] + m * 1024);
#pragma unroll
        for (int n = 0; n < 2; ++n)
          b[ks][n] = *(const short8*)(smem + Bb + boffs[ks] + n * 1024);
      }
      stB(Tn + 1, 0);
      FEN(); BARX(); FEN();
      MFMA_Q(0, 0);
      FEN(); BARX(); FEN();
      // ---- P1/P5: b[v1]; stage B(Tn+1).h1 ----
#pragma unroll
      for (int ks = 0; ks < 2; ++ks)
#pragma unroll
        for (int n = 2; n < 4; ++n)
          b[ks][n] = *(const short8*)(smem + Bb + boffs[ks] + n * 1024);
      stB(Tn + 1, 1);
      FEN(); BARX(); FEN();
      MFMA_Q(0, 2);
      FEN(); BARX(); FEN();
      // ---- P2/P6: a[hi half]; stage A(Tn+2).q0 ----
#pragma unroll
      for (int ks = 0; ks < 2; ++ks)
#pragma unroll
        for (int m = 0; m < MF / 2; ++m)
          a[ks][m] = *(const short8*)(smem + Ab + aoffs[ks] + (MF / 2 + m) * 1024);
      stA(Tn + 2, 0);
      FEN(); BARX(); FEN();
      MFMA_Q(MF / 2, 2);
      FEN(); BARX(); FEN();
      // ---- P3/P7: stage A(Tn+2).q1; MFMA; guard-before-barrier ----
      stA(Tn + 2, 1);
      FEN(); BARX(); FEN();
      MFMA_Q(MF / 2, 0);
      if (half == 0) {
        if (notlast) { GUARD_CNT(); } else { VMW0(); }
      } else {
        GUARD_CNT();
      }
      FEN(); BARX(); FEN();
    }
  }
#undef MFMA_Q
#undef GUARD_CNT

  // ---------- epilogue ----------
  int rowl = lane >> 4, coll = lane & 15;
  if (GID == 0) {
    int j0h = jb * 128;
#pragma unroll
    for (int pair = 0; pair < 2; ++pair) {
      int hcol = j0h + (2 * wc + pair) * 16 + coll;
      float ba = bias[e * 2 * HID + hcol];
      float bb = bias[e * 2 * HID + HID + hcol];
#pragma unroll
      for (int m = 0; m < MF; ++m)
#pragma unroll
        for (int j = 0; j < 4; ++j) {
          int grow = row0 + wr * (BM / 2) + m * 16 + rowl * 4 + j;
          if (grow < cntE) {
            float av = acc[m][2 * pair][j] + ba;
            float bv = acc[m][2 * pair + 1][j] + bb;
            float hv = av / (1.f + __expf(-av)) * bv;
            hb[(size_t)(base + grow) * HID + hcol] = f2bf(hv);
          }
        }
    }
  } else {
    int j0 = jb * 256;
    float bv[4];
#pragma unroll
    for (int n = 0; n < 4; ++n) bv[n] = bias[e * DIM + j0 + wc * 64 + n * 16 + coll];
#pragma unroll
    for (int m = 0; m < MF; ++m)
#pragma unroll
      for (int j = 0; j < 4; ++j) {
        int grow = row0 + wr * (BM / 2) + m * 16 + rowl * 4 + j;
        if (grow < cntE) {
          int tok = rows[base + grow];
          float g = rowg[base + grow];
#pragma unroll
          for (int n = 0; n < 4; ++n) {
            int col = j0 + wc * 64 + n * 16 + coll;
            atomicAdd(&out[(size_t)tok * DIM + col], g * (acc[m][n][j] + bv[n]));
          }
        }
      }
  }
}

extern "C" void kernel_launch(void* const* d_in, const int* in_sizes, int n_in,
                              void* d_out, int out_size, void* d_ws, size_t ws_size,
                              hipStream_t stream) {
  (void)in_sizes; (void)n_in; (void)out_size;
  const float* x  = (const float*)d_in[0];
  const float* Wr = (const float*)d_in[1];
  const float* W1 = (const float*)d_in[2];
  const float* b1 = (const float*)d_in[3];
  const float* W2 = (const float*)d_in[4];
  const float* b2 = (const float*)d_in[5];
  float* out = (float*)d_out;
  char* ws = (char*)d_ws;

  const size_t o_xb   = 0;
  const size_t o_w1t  = o_xb   + (size_t)N_TOK * DIM * 2;
  const size_t o_w2t  = o_w1t  + (size_t)NEXP * 2 * HID * DIM * 2;
  const size_t o_hb   = o_w2t  + (size_t)NEXP * DIM * HID * 2;
  const size_t o_rows = o_hb   + (size_t)NK * HID * 2;
  const size_t o_rowg = o_rows + (size_t)NK * 4;
  const size_t o_te   = o_rowg + (size_t)NK * 4;
  const size_t o_tg   = o_te   + (size_t)NK * 4;
  const size_t o_offs = o_tg   + (size_t)NK * 4;
  const size_t o_t2   = o_offs + 64;
  const size_t o_t1   = o_t2   + 64;
  const size_t need   = o_t1   + 64;
  if (ws_size < need) return;

  unsigned short* xb  = (unsigned short*)(ws + o_xb);
  unsigned short* w1t = (unsigned short*)(ws + o_w1t);
  unsigned short* w2t = (unsigned short*)(ws + o_w2t);
  unsigned short* hb  = (unsigned short*)(ws + o_hb);
  int*   rows = (int*)(ws + o_rows);
  float* rowg = (float*)(ws + o_rowg);
  int*   te   = (int*)(ws + o_te);
  float* tg   = (float*)(ws + o_tg);
  int*   offs = (int*)(ws + o_offs);
  int*   tl256 = (int*)(ws + o_t2);
  int*   tl128 = (int*)(ws + o_t1);

  prep_k<<<10240, 256, 0, stream>>>(x, Wr, W1, w1t, xb, te, tg);
  sortscan_k<<<1, 1024, 0, stream>>>(te, tg, offs, tl256, tl128, rows, rowg);
  moe_gemm8p<0, 256><<<dim3(HID / 128, AUXY), 512, 0, stream>>>(
      xb, w1t, b1, hb, nullptr, rows, rowg, offs, tl256, W2, w2t, out);
  moe_gemm8p<1, 128><<<dim3(DIM / 256, MAXT1), 512, 0, stream>>>(
      hb, w2t, b2, nullptr, out, rows, rowg, offs, tl128, nullptr, nullptr, nullptr);
}